// Round 9
// baseline (449.168 us; speedup 1.0000x reference)
//
#include <hip/hip_runtime.h>
#include <hip/hip_bf16.h>

#define D  64     // feature dim == units
#define CH 4096   // edges per chunk
#define AS 68     // acc row stride in floats (padded: conflict-free, 16B-aligned)

// ---------------------------------------------------------------------------
// K1: blocks [0, gemmTiles): Z = emb @ W (bf16 out).  Blocks [gemmTiles, +NC):
// per-chunk bucket histogram (native LDS atomics) + per-edge local rank.
// ---------------------------------------------------------------------------
__global__ __launch_bounds__(256) void gemm_part(
    const float* __restrict__ emb,
    const float* __restrict__ W,
    __hip_bfloat16* __restrict__ Zb,
    const int*   __restrict__ dst,
    int*         __restrict__ histG,   // [NC * NB], chunk-major
    ushort*      __restrict__ lrank,   // [E]
    int N, int E, int NB, int gemmTiles)
{
    __shared__ int smem[4096];   // partition: hist[NB<=782]; gemm: 64x64 tile

    if ((int)blockIdx.x >= gemmTiles) {
        const int c  = (int)blockIdx.x - gemmTiles;
        const int t  = threadIdx.x;
        for (int b = t; b < NB; b += 256) smem[b] = 0;
        __syncthreads();
        const int e0 = c * CH;
#pragma unroll
        for (int i = 0; i < 16; ++i) {
            int e = e0 + i * 256 + t;
            if (e < E) {
                int b = dst[e] >> 6;
                lrank[e] = (ushort)atomicAdd(&smem[b], 1);   // ds_add_rtn_u32
            }
        }
        __syncthreads();
        for (int b = t; b < NB; b += 256)
            histG[(size_t)c * NB + b] = smem[b];
        return;
    }

    const int lane = threadIdx.x & 63;
    const int wave = threadIdx.x >> 6;

    float wcol[D];
#pragma unroll
    for (int k = 0; k < D; ++k) wcol[k] = W[k * D + lane];

    float* At = (float*)smem;  // 64 x 64
    const int row0 = blockIdx.x * 64;

    for (int i = threadIdx.x; i < 1024; i += 256) {
        int r  = i >> 4;
        int gr = row0 + r;
        float4 v;
        if (gr < N) v = reinterpret_cast<const float4*>(emb)[(size_t)gr * 16 + (i & 15)];
        else        v = float4{0.f, 0.f, 0.f, 0.f};
        reinterpret_cast<float4*>(At)[i] = v;
    }
    __syncthreads();

    for (int rr = 0; rr < 16; ++rr) {
        int r  = wave * 16 + rr;
        int gr = row0 + r;
        if (gr >= N) break;
        const float4* arow = reinterpret_cast<const float4*>(At + r * D);
        float acc = 0.f;
#pragma unroll
        for (int k4 = 0; k4 < 16; ++k4) {
            float4 a = arow[k4];
            acc = fmaf(a.x, wcol[4 * k4 + 0], acc);
            acc = fmaf(a.y, wcol[4 * k4 + 1], acc);
            acc = fmaf(a.z, wcol[4 * k4 + 2], acc);
            acc = fmaf(a.w, wcol[4 * k4 + 3], acc);
        }
        Zb[(size_t)gr * D + lane] = __float2bfloat16(acc);
    }
}

// ---------------------------------------------------------------------------
// K2: exclusive scan over hist in BUCKET-MAJOR order (m = b*NC + c), values
// gathered from chunk-major histG.  4096 elems/block; partials <= 256
// inline-scanned by consumers.
// ---------------------------------------------------------------------------
__global__ __launch_bounds__(256) void scan_hist(
    const int* __restrict__ histG, int* __restrict__ offsets,
    int* __restrict__ partials, int NB, int NC, int M)
{
    __shared__ int sh[256];
    const int t    = threadIdx.x;
    const int base = blockIdx.x * 4096 + t * 16;

    int v[16], ps[16];
    int b = base / NC, c = base - b * NC;
#pragma unroll
    for (int k = 0; k < 16; ++k) {
        int m = base + k;
        v[k] = (m < M) ? histG[(size_t)c * NB + b] : 0;
        if (++c == NC) { c = 0; ++b; }
    }
    int s = 0;
#pragma unroll
    for (int k = 0; k < 16; ++k) { ps[k] = s; s += v[k]; }
    sh[t] = s;
    __syncthreads();
    for (int off = 1; off < 256; off <<= 1) {
        int x = (t >= off) ? sh[t - off] : 0;
        __syncthreads();
        sh[t] += x;
        __syncthreads();
    }
    const int excl = sh[t] - s;
#pragma unroll
    for (int k = 0; k < 4; ++k) {
        int4 o;
        o.x = excl + ps[4*k+0]; o.y = excl + ps[4*k+1];
        o.z = excl + ps[4*k+2]; o.w = excl + ps[4*k+3];
        reinterpret_cast<int4*>(offsets + base)[k] = o;
    }
    if (t == 255) partials[blockIdx.x] = sh[255];
}

__device__ __forceinline__ void scan_partials_lds256(
    const int* __restrict__ partials, int nb, int* sp)
{
    const int t    = threadIdx.x;
    const int orig = (t < nb) ? partials[t] : 0;
    sp[t] = orig;
    __syncthreads();
    for (int off = 1; off < 256; off <<= 1) {
        int x = (t >= off) ? sp[t - off] : 0;
        __syncthreads();
        sp[t] += x;
        __syncthreads();
    }
    int incl = sp[t];
    __syncthreads();
    sp[t] = incl - orig;  // exclusive
    __syncthreads();
}

// ---------------------------------------------------------------------------
// K3: scatter into bucket-grouped edge array.  Stage the chunk's records
// sorted by bucket in LDS, then write out: consecutive LDS slots in the same
// bucket land at consecutive global positions.  NO atomics.
// rec.x packs src (16 bits, N<65536) | (dst&63) << 16;  rec.y = w bits.
// ---------------------------------------------------------------------------
__global__ __launch_bounds__(256) void scatter_bkt(
    const int*    __restrict__ src,
    const int*    __restrict__ dst,
    const float*  __restrict__ w,
    const ushort* __restrict__ lrank,
    const int*    __restrict__ histG,
    const int*    __restrict__ offsets,
    const int*    __restrict__ partials,
    int2*         __restrict__ csr,
    int E, int NB, int NC, int nb2)
{
    __shared__ int2   rec[CH];      // 32 KB
    __shared__ ushort bidv[CH];     // 8 KB
    __shared__ int    delta[784];   // localBase, then (globalOff - localBase)
    __shared__ int    sh[256];
    __shared__ int    sp[256];
    scan_partials_lds256(partials, nb2, sp);

    const int t  = threadIdx.x;
    const int c  = blockIdx.x;
    const int e0 = c * CH;
    const int cnt = min(CH, E - e0);

    // local exclusive scan of this chunk's histogram (4 buckets per thread)
    int hv[4], hps[4];
    const int hbase = t * 4;
#pragma unroll
    for (int k = 0; k < 4; ++k) {
        int b = hbase + k;
        hv[k] = (b < NB) ? histG[(size_t)c * NB + b] : 0;
    }
    int s = 0;
#pragma unroll
    for (int k = 0; k < 4; ++k) { hps[k] = s; s += hv[k]; }
    sh[t] = s;
    __syncthreads();
    for (int off = 1; off < 256; off <<= 1) {
        int x = (t >= off) ? sh[t - off] : 0;
        __syncthreads();
        sh[t] += x;
        __syncthreads();
    }
    const int hexcl = sh[t] - s;
#pragma unroll
    for (int k = 0; k < 4; ++k) {
        int b = hbase + k;
        if (b < NB) delta[b] = hexcl + hps[k];   // localBase[b]
    }
    __syncthreads();

    // stage records sorted by bucket
#pragma unroll
    for (int i = 0; i < 16; ++i) {
        int e = e0 + i * 256 + t;
        if (e < E) {
            int d  = dst[e];
            int b  = d >> 6;
            int lp = delta[b] + lrank[e];
            rec[lp]  = make_int2(src[e] | ((d & 63) << 16), __float_as_int(w[e]));
            bidv[lp] = (ushort)b;
        }
    }
    __syncthreads();

    // delta[b] := globalChunkOff(b,c) - localBase[b]
#pragma unroll
    for (int k = 0; k < 4; ++k) {
        int b = hbase + k;
        if (b < NB) {
            int m = b * NC + c;
            delta[b] = offsets[m] + sp[m >> 12] - delta[b];
        }
    }
    __syncthreads();

    for (int j = t; j < cnt; j += 256)
        csr[j + delta[bidv[j]]] = rec[j];
}

// ---------------------------------------------------------------------------
// K4: one block per 64-node bucket.  Accumulate w * Z[src] into a padded LDS
// tile via NATIVE ds_add_f32 (HIP atomicAdd on __shared__ float — hardware
// LDS float atomic, unlike __hip_atomic_fetch_add which CAS-loops), then
// relu + coalesced store.  4 waves x 4 slots = 16 edges in flight per block.
// ---------------------------------------------------------------------------
__global__ __launch_bounds__(256) void aggregate(
    const __hip_bfloat16* __restrict__ Zb,
    const int2* __restrict__ csr,
    const int*  __restrict__ offsets,
    const int*  __restrict__ partials,
    float*      __restrict__ out,
    int N, int E, int NB, int NC, int nb2)
{
    __shared__ float acc[64 * AS];
    __shared__ int   sp[256];
    scan_partials_lds256(partials, nb2, sp);

    const int t = threadIdx.x;
    const int b = blockIdx.x;

    for (int i = t; i < 64 * AS; i += 256) acc[i] = 0.f;

    const int m0 = b * NC;
    const int bStart = offsets[m0] + sp[m0 >> 12];
    int bEnd;
    if (b + 1 < NB) { int m1 = (b + 1) * NC; bEnd = offsets[m1] + sp[m1 >> 12]; }
    else            bEnd = E;
    __syncthreads();

    const int wv   = t >> 6;
    const int lane = t & 63;
    const int slot = lane >> 4;
    const int q    = lane & 15;

    const int len  = bEnd - bStart;
    const int wBeg = bStart + ((len * wv) >> 2);
    const int wEnd = bStart + ((len * (wv + 1)) >> 2);

    const ushort4* Zu = reinterpret_cast<const ushort4*>(Zb);

    int  j   = wBeg + slot;
    int2 cur = (j < wEnd) ? csr[j] : make_int2(0, 0);
    while (j < wEnd) {
        const int jn  = j + 4;
        int2      nxt = (jn < wEnd) ? csr[jn] : make_int2(0, 0);
        float     ww  = __int_as_float(cur.y);
        int       sn  = cur.x & 0xFFFF;
        int       dl  = (cur.x >> 16) & 63;
        ushort4   zu  = Zu[(size_t)sn * 16 + q];
        float* ap = &acc[dl * AS + q * 4];
        atomicAdd(ap + 0, ww * __uint_as_float((unsigned)zu.x << 16));  // ds_add_f32
        atomicAdd(ap + 1, ww * __uint_as_float((unsigned)zu.y << 16));
        atomicAdd(ap + 2, ww * __uint_as_float((unsigned)zu.z << 16));
        atomicAdd(ap + 3, ww * __uint_as_float((unsigned)zu.w << 16));
        cur = nxt;
        j   = jn;
    }
    __syncthreads();

    const int node0 = b << 6;
    for (int i = t; i < 1024; i += 256) {   // 64 rows x 16 float4
        int r = i >> 4, qq = i & 15;
        int node = node0 + r;
        if (node < N) {
            const float* ap = &acc[r * AS + qq * 4];
            float4 o;
            o.x = fmaxf(ap[0], 0.f);
            o.y = fmaxf(ap[1], 0.f);
            o.z = fmaxf(ap[2], 0.f);
            o.w = fmaxf(ap[3], 0.f);
            reinterpret_cast<float4*>(out)[(size_t)node * 16 + qq] = o;
        }
    }
}

// ---------------------------------------------------------------------------
extern "C" void kernel_launch(void* const* d_in, const int* in_sizes, int n_in,
                              void* d_out, int out_size, void* d_ws, size_t ws_size,
                              hipStream_t stream)
{
    const float* emb  = (const float*)d_in[0];  // [N, 64]
    const int*   esrc = (const int*)  d_in[1];  // [E]
    const int*   edst = (const int*)  d_in[2];  // [E]
    const float* ew   = (const float*)d_in[3];  // [E]
    const float* W    = (const float*)d_in[4];  // [64, 64]
    float*       out  = (float*)d_out;          // [N, 64]

    const int N  = in_sizes[0] / D;
    const int E  = in_sizes[1];

    const int NB  = (N + 63) / 64;       // 782 buckets of 64 nodes
    const int NC  = (E + CH - 1) / CH;   // 196 chunks
    const int M   = NB * NC;             // 153,272 scan elements
    const int nb2 = (M + 4095) / 4096;   // 38 scan blocks (<= 256)
    const int Mpad = nb2 * 4096;

    // Workspace (~16 MB), all segments 16 B aligned.
    char* p = (char*)d_ws;
    __hip_bfloat16* Zb = (__hip_bfloat16*)p;  p += (size_t)N * D * 2;   // 6.4 MB
    int*    histG   = (int*)p;                p += (size_t)Mpad * 4;    // 0.62 MB
    int*    offsets = (int*)p;                p += (size_t)Mpad * 4;    // 0.62 MB
    int*    partials= (int*)p;                p += 256 * 4;
    ushort* lrank   = (ushort*)p;             p += (size_t)((E + 7) & ~7) * 2; // 1.6 MB
    int2*   csr     = (int2*)p;                                         // 6.4 MB

    const int gemmTiles = (N + 63) / 64;
    gemm_part<<<gemmTiles + NC, 256, 0, stream>>>(
        emb, W, Zb, edst, histG, lrank, N, E, NB, gemmTiles);

    scan_hist<<<nb2, 256, 0, stream>>>(histG, offsets, partials, NB, NC, M);

    scatter_bkt<<<NC, 256, 0, stream>>>(
        esrc, edst, ew, lrank, histG, offsets, partials, csr, E, NB, NC, nb2);

    aggregate<<<NB, 256, 0, stream>>>(
        Zb, csr, offsets, partials, out, N, E, NB, NC, nb2);
}

// Round 10
// 145.478 us; speedup vs baseline: 3.0875x; 3.0875x over previous
//
#include <hip/hip_runtime.h>
#include <hip/hip_bf16.h>

#define D    64    // feature dim == units
#define CH   4096  // edges per chunk (K1/K3)
#define PASS 2048  // edges staged per pass in K4

// ---------------------------------------------------------------------------
// K1: blocks [0, gemmTiles): Z = emb @ W (bf16 out).  Blocks [gemmTiles, +NC):
// per-chunk bucket histogram (native int LDS atomics) + per-edge local rank.
// ---------------------------------------------------------------------------
__global__ __launch_bounds__(256) void gemm_part(
    const float* __restrict__ emb,
    const float* __restrict__ W,
    __hip_bfloat16* __restrict__ Zb,
    const int*   __restrict__ dst,
    int*         __restrict__ histG,   // [NC * NB], chunk-major
    ushort*      __restrict__ lrank,   // [E]
    int N, int E, int NB, int gemmTiles)
{
    __shared__ int smem[4096];   // partition: hist[NB<=782]; gemm: 64x64 tile

    if ((int)blockIdx.x >= gemmTiles) {
        const int c  = (int)blockIdx.x - gemmTiles;
        const int t  = threadIdx.x;
        for (int b = t; b < NB; b += 256) smem[b] = 0;
        __syncthreads();
        const int e0 = c * CH;
#pragma unroll
        for (int i = 0; i < 16; ++i) {
            int e = e0 + i * 256 + t;
            if (e < E) {
                int b = dst[e] >> 6;
                lrank[e] = (ushort)atomicAdd(&smem[b], 1);   // ds_add_rtn_u32
            }
        }
        __syncthreads();
        for (int b = t; b < NB; b += 256)
            histG[(size_t)c * NB + b] = smem[b];
        return;
    }

    const int lane = threadIdx.x & 63;
    const int wave = threadIdx.x >> 6;

    float wcol[D];
#pragma unroll
    for (int k = 0; k < D; ++k) wcol[k] = W[k * D + lane];

    float* At = (float*)smem;  // 64 x 64
    const int row0 = blockIdx.x * 64;

    for (int i = threadIdx.x; i < 1024; i += 256) {
        int r  = i >> 4;
        int gr = row0 + r;
        float4 v;
        if (gr < N) v = reinterpret_cast<const float4*>(emb)[(size_t)gr * 16 + (i & 15)];
        else        v = float4{0.f, 0.f, 0.f, 0.f};
        reinterpret_cast<float4*>(At)[i] = v;
    }
    __syncthreads();

    for (int rr = 0; rr < 16; ++rr) {
        int r  = wave * 16 + rr;
        int gr = row0 + r;
        if (gr >= N) break;
        const float4* arow = reinterpret_cast<const float4*>(At + r * D);
        float acc = 0.f;
#pragma unroll
        for (int k4 = 0; k4 < 16; ++k4) {
            float4 a = arow[k4];
            acc = fmaf(a.x, wcol[4 * k4 + 0], acc);
            acc = fmaf(a.y, wcol[4 * k4 + 1], acc);
            acc = fmaf(a.z, wcol[4 * k4 + 2], acc);
            acc = fmaf(a.w, wcol[4 * k4 + 3], acc);
        }
        Zb[(size_t)gr * D + lane] = __float2bfloat16(acc);
    }
}

// ---------------------------------------------------------------------------
// K2: exclusive scan over hist in BUCKET-MAJOR order (m = b*NC + c), values
// gathered from chunk-major histG.  4096 elems/block; partials <= 256
// inline-scanned by consumers.
// ---------------------------------------------------------------------------
__global__ __launch_bounds__(256) void scan_hist(
    const int* __restrict__ histG, int* __restrict__ offsets,
    int* __restrict__ partials, int NB, int NC, int M)
{
    __shared__ int sh[256];
    const int t    = threadIdx.x;
    const int base = blockIdx.x * 4096 + t * 16;

    int v[16], ps[16];
    int b = base / NC, c = base - b * NC;
#pragma unroll
    for (int k = 0; k < 16; ++k) {
        int m = base + k;
        v[k] = (m < M) ? histG[(size_t)c * NB + b] : 0;
        if (++c == NC) { c = 0; ++b; }
    }
    int s = 0;
#pragma unroll
    for (int k = 0; k < 16; ++k) { ps[k] = s; s += v[k]; }
    sh[t] = s;
    __syncthreads();
    for (int off = 1; off < 256; off <<= 1) {
        int x = (t >= off) ? sh[t - off] : 0;
        __syncthreads();
        sh[t] += x;
        __syncthreads();
    }
    const int excl = sh[t] - s;
#pragma unroll
    for (int k = 0; k < 4; ++k) {
        int4 o;
        o.x = excl + ps[4*k+0]; o.y = excl + ps[4*k+1];
        o.z = excl + ps[4*k+2]; o.w = excl + ps[4*k+3];
        reinterpret_cast<int4*>(offsets + base)[k] = o;
    }
    if (t == 255) partials[blockIdx.x] = sh[255];
}

__device__ __forceinline__ void scan_partials_lds256(
    const int* __restrict__ partials, int nb, int* sp)
{
    const int t    = threadIdx.x;
    const int orig = (t < nb) ? partials[t] : 0;
    sp[t] = orig;
    __syncthreads();
    for (int off = 1; off < 256; off <<= 1) {
        int x = (t >= off) ? sp[t - off] : 0;
        __syncthreads();
        sp[t] += x;
        __syncthreads();
    }
    int incl = sp[t];
    __syncthreads();
    sp[t] = incl - orig;  // exclusive
    __syncthreads();
}

// ---------------------------------------------------------------------------
// K3: scatter into bucket-grouped edge array (staged sorted in LDS, runs of
// consecutive global writes).  NO atomics.
// rec.x packs src (16 bits, N<65536) | (dst&63) << 16;  rec.y = w bits.
// ---------------------------------------------------------------------------
__global__ __launch_bounds__(256) void scatter_bkt(
    const int*    __restrict__ src,
    const int*    __restrict__ dst,
    const float*  __restrict__ w,
    const ushort* __restrict__ lrank,
    const int*    __restrict__ histG,
    const int*    __restrict__ offsets,
    const int*    __restrict__ partials,
    int2*         __restrict__ csr,
    int E, int NB, int NC, int nb2)
{
    __shared__ int2   rec[CH];      // 32 KB
    __shared__ ushort bidv[CH];     // 8 KB
    __shared__ int    delta[784];
    __shared__ int    sh[256];
    __shared__ int    sp[256];
    scan_partials_lds256(partials, nb2, sp);

    const int t  = threadIdx.x;
    const int c  = blockIdx.x;
    const int e0 = c * CH;
    const int cnt = min(CH, E - e0);

    int hv[4], hps[4];
    const int hbase = t * 4;
#pragma unroll
    for (int k = 0; k < 4; ++k) {
        int b = hbase + k;
        hv[k] = (b < NB) ? histG[(size_t)c * NB + b] : 0;
    }
    int s = 0;
#pragma unroll
    for (int k = 0; k < 4; ++k) { hps[k] = s; s += hv[k]; }
    sh[t] = s;
    __syncthreads();
    for (int off = 1; off < 256; off <<= 1) {
        int x = (t >= off) ? sh[t - off] : 0;
        __syncthreads();
        sh[t] += x;
        __syncthreads();
    }
    const int hexcl = sh[t] - s;
#pragma unroll
    for (int k = 0; k < 4; ++k) {
        int b = hbase + k;
        if (b < NB) delta[b] = hexcl + hps[k];   // localBase[b]
    }
    __syncthreads();

#pragma unroll
    for (int i = 0; i < 16; ++i) {
        int e = e0 + i * 256 + t;
        if (e < E) {
            int d  = dst[e];
            int b  = d >> 6;
            int lp = delta[b] + lrank[e];
            rec[lp]  = make_int2(src[e] | ((d & 63) << 16), __float_as_int(w[e]));
            bidv[lp] = (ushort)b;
        }
    }
    __syncthreads();

#pragma unroll
    for (int k = 0; k < 4; ++k) {
        int b = hbase + k;
        if (b < NB) {
            int m = b * NC + c;
            delta[b] = offsets[m] + sp[m >> 12] - delta[b];
        }
    }
    __syncthreads();

    for (int j = t; j < cnt; j += 256)
        csr[j + delta[bidv[j]]] = rec[j];
}

// ---------------------------------------------------------------------------
// K4: one block per 64-node bucket.  Per <=2048-edge pass: sort the pass's
// edges by destination node in LDS (native int LDS atomics + 64-wide shfl
// scan — NO FP atomics), then each wave register-gathers its 16 nodes:
// slot = lane>>4 walks the node's contiguous LDS edge list, q = lane&15
// loads 8 B of the bf16 Z row.  float4 acc in VGPRs across passes;
// shfl_down reduce; coalesced 256 B row store + relu.
// ---------------------------------------------------------------------------
__global__ __launch_bounds__(256) void aggregate(
    const __hip_bfloat16* __restrict__ Zb,
    const int2* __restrict__ csr,
    const int*  __restrict__ offsets,
    const int*  __restrict__ partials,
    float*      __restrict__ out,
    int N, int E, int NB, int NC, int nb2)
{
    __shared__ int2 srec[PASS];   // 16 KB
    __shared__ int  hist[64];
    __shared__ int  nbase[65];
    __shared__ int  sp[256];
    scan_partials_lds256(partials, nb2, sp);

    const int t = threadIdx.x;
    const int b = blockIdx.x;

    const int m0 = b * NC;
    const int bStart = offsets[m0] + sp[m0 >> 12];
    int bEnd;
    if (b + 1 < NB) { int m1 = (b + 1) * NC; bEnd = offsets[m1] + sp[m1 >> 12]; }
    else            bEnd = E;

    const int wv   = t >> 6;
    const int lane = t & 63;
    const int slot = lane >> 4;
    const int q    = lane & 15;

    const ushort4* Zu = reinterpret_cast<const ushort4*>(Zb);

    float4 acc[16];
#pragma unroll
    for (int r = 0; r < 16; ++r) acc[r] = float4{0.f, 0.f, 0.f, 0.f};

    for (int cur = bStart; cur < bEnd; cur += PASS) {
        const int cnt = min(PASS, bEnd - cur);

        if (t < 64) hist[t] = 0;
        __syncthreads();

        // load + local rank (static register indexing, <=8 edges/thread)
        int2 myrec[8]; int mypos[8];
#pragma unroll
        for (int k = 0; k < 8; ++k) {
            int j = k * 256 + t;
            if (j < cnt) {
                int2 r2 = csr[cur + j];
                myrec[k] = r2;
                mypos[k] = atomicAdd(&hist[(r2.x >> 16) & 63], 1);  // ds_add_rtn_u32
            }
        }
        __syncthreads();

        // exclusive scan of 64-entry hist (wave 0)
        if (t < 64) {
            int v = hist[t];
            int x = v;
            for (int off = 1; off < 64; off <<= 1) {
                int y = __shfl_up(x, off, 64);
                if (t >= off) x += y;
            }
            nbase[t] = x - v;
            if (t == 63) nbase[64] = x;   // == cnt
        }
        __syncthreads();

        // scatter into node-sorted LDS
#pragma unroll
        for (int k = 0; k < 8; ++k) {
            int j = k * 256 + t;
            if (j < cnt)
                srec[nbase[(myrec[k].x >> 16) & 63] + mypos[k]] = myrec[k];
        }
        __syncthreads();

        // register gather: wave wv owns nodes [wv*16, wv*16+16)
        for (int r = 0; r < 16; ++r) {
            const int nl = wv * 16 + r;
            const int je = nbase[nl + 1];
            for (int j = nbase[nl] + slot; j < je; j += 4) {
                int2   e  = srec[j];
                float  ww = __int_as_float(e.y);
                int    sn = e.x & 0xFFFF;
                ushort4 zu = Zu[(size_t)sn * 16 + q];
                acc[r].x = fmaf(ww, __uint_as_float((unsigned)zu.x << 16), acc[r].x);
                acc[r].y = fmaf(ww, __uint_as_float((unsigned)zu.y << 16), acc[r].y);
                acc[r].z = fmaf(ww, __uint_as_float((unsigned)zu.z << 16), acc[r].z);
                acc[r].w = fmaf(ww, __uint_as_float((unsigned)zu.w << 16), acc[r].w);
            }
        }
        __syncthreads();   // protect srec before next pass
    }

    // reduce slots + store
    const int node0 = (b << 6) + wv * 16;
#pragma unroll
    for (int r = 0; r < 16; ++r) {
        float4 a = acc[r];
#pragma unroll
        for (int off = 32; off >= 16; off >>= 1) {
            a.x += __shfl_down(a.x, off, 64);
            a.y += __shfl_down(a.y, off, 64);
            a.z += __shfl_down(a.z, off, 64);
            a.w += __shfl_down(a.w, off, 64);
        }
        int node = node0 + r;
        if (lane < 16 && node < N) {
            float4 o;
            o.x = fmaxf(a.x, 0.f);
            o.y = fmaxf(a.y, 0.f);
            o.z = fmaxf(a.z, 0.f);
            o.w = fmaxf(a.w, 0.f);
            reinterpret_cast<float4*>(out)[(size_t)node * 16 + lane] = o;
        }
    }
}

// ---------------------------------------------------------------------------
extern "C" void kernel_launch(void* const* d_in, const int* in_sizes, int n_in,
                              void* d_out, int out_size, void* d_ws, size_t ws_size,
                              hipStream_t stream)
{
    const float* emb  = (const float*)d_in[0];  // [N, 64]
    const int*   esrc = (const int*)  d_in[1];  // [E]
    const int*   edst = (const int*)  d_in[2];  // [E]
    const float* ew   = (const float*)d_in[3];  // [E]
    const float* W    = (const float*)d_in[4];  // [64, 64]
    float*       out  = (float*)d_out;          // [N, 64]

    const int N  = in_sizes[0] / D;
    const int E  = in_sizes[1];

    const int NB  = (N + 63) / 64;       // 782 buckets of 64 nodes
    const int NC  = (E + CH - 1) / CH;   // 196 chunks
    const int M   = NB * NC;             // 153,272 scan elements
    const int nb2 = (M + 4095) / 4096;   // 38 scan blocks (<= 256)
    const int Mpad = nb2 * 4096;

    // Workspace (~16 MB), all segments 16 B aligned.
    char* p = (char*)d_ws;
    __hip_bfloat16* Zb = (__hip_bfloat16*)p;  p += (size_t)N * D * 2;   // 6.4 MB
    int*    histG   = (int*)p;                p += (size_t)Mpad * 4;    // 0.62 MB
    int*    offsets = (int*)p;                p += (size_t)Mpad * 4;    // 0.62 MB
    int*    partials= (int*)p;                p += 256 * 4;
    ushort* lrank   = (ushort*)p;             p += (size_t)((E + 7) & ~7) * 2; // 1.6 MB
    int2*   csr     = (int2*)p;                                         // 6.4 MB

    const int gemmTiles = (N + 63) / 64;
    gemm_part<<<gemmTiles + NC, 256, 0, stream>>>(
        emb, W, Zb, edst, histG, lrank, N, E, NB, gemmTiles);

    scan_hist<<<nb2, 256, 0, stream>>>(histG, offsets, partials, NB, NC, M);

    scatter_bkt<<<NC, 256, 0, stream>>>(
        esrc, edst, ew, lrank, histG, offsets, partials, csr, E, NB, NC, nb2);

    aggregate<<<NB, 256, 0, stream>>>(
        Zb, csr, offsets, partials, out, N, E, NB, NC, nb2);
}